// Round 2
// baseline (820.269 us; speedup 1.0000x reference)
//
#include <hip/hip_runtime.h>
#include <stdint.h>

#define B 2
#define N_PROP 2000
#define MAX_GT 50
#define IMG_H 1024
#define IMG_W 1024
#define TRAIN_ROIS 200
#define POS_CAP 66
#define NEG_CAP 134
#define MASK_H 28
#define MASK_W 28

// JAX threefry2x32: 20 rounds, key injection every 4 rounds.
__device__ __forceinline__ void threefry(uint32_t k0, uint32_t k1,
                                         uint32_t x0, uint32_t x1,
                                         uint32_t& o0, uint32_t& o1) {
  uint32_t k2 = k0 ^ k1 ^ 0x1BD11BDAu;
  x0 += k0; x1 += k1;
#define TF_R(r) { x0 += x1; x1 = (x1 << (r)) | (x1 >> (32 - (r))); x1 ^= x0; }
  TF_R(13) TF_R(15) TF_R(26) TF_R(6)
  x0 += k1; x1 += k2 + 1u;
  TF_R(17) TF_R(29) TF_R(16) TF_R(24)
  x0 += k2; x1 += k0 + 2u;
  TF_R(13) TF_R(15) TF_R(26) TF_R(6)
  x0 += k0; x1 += k1 + 3u;
  TF_R(17) TF_R(29) TF_R(16) TF_R(24)
  x0 += k1; x1 += k2 + 4u;
  TF_R(13) TF_R(15) TF_R(26) TF_R(6)
  x0 += k2; x1 += k0 + 5u;
#undef TF_R
  o0 = x0; o1 = x1;
}

__device__ __forceinline__ float bits_to_uniform(uint32_t bits) {
  return __uint_as_float((bits >> 9) | 0x3F800000u) - 1.0f;
}

// Kernel 1: per-image selection. One block per image.
__global__ __launch_bounds__(1024) void dtl_select(
    const float* __restrict__ proposals,   // [B, N_PROP, 4]
    const int* __restrict__ gt_class_ids,  // [B, MAX_GT]
    const float* __restrict__ gt_boxes,    // [B, MAX_GT, 4]
    float* __restrict__ out,               // full flat output
    int* __restrict__ ws_meta,             // per image 72 ints: [p, n, assign[66]...]
    float* __restrict__ ws_boxes)          // [B, POS_CAP, 4]
{
#pragma clang fp contract(off)
  const int b = blockIdx.x;
  const int tid = threadIdx.x;
  const int NT = blockDim.x;

  __shared__ float s_gt[MAX_GT][4];
  __shared__ int   s_cls[MAX_GT];
  __shared__ int   s_flag[MAX_GT];   // 0 invalid, 1 crowd, 2 noncrowd
  __shared__ float s_ps[N_PROP];     // positive scores (-1 if not candidate)
  __shared__ float s_ns[N_PROP];     // negative scores (-1 if not candidate)
  __shared__ int   s_cnt[2];
  __shared__ int   s_selpos[POS_CAP];
  __shared__ int   s_selneg[NEG_CAP];

  if (tid < 2) s_cnt[tid] = 0;
  if (tid < MAX_GT) {
    float g0 = gt_boxes[((size_t)b * MAX_GT + tid) * 4 + 0];
    float g1 = gt_boxes[((size_t)b * MAX_GT + tid) * 4 + 1];
    float g2 = gt_boxes[((size_t)b * MAX_GT + tid) * 4 + 2];
    float g3 = gt_boxes[((size_t)b * MAX_GT + tid) * 4 + 3];
    s_gt[tid][0] = g0; s_gt[tid][1] = g1; s_gt[tid][2] = g2; s_gt[tid][3] = g3;
    int c = gt_class_ids[b * MAX_GT + tid];
    s_cls[tid] = c;
    bool vg = (fabsf(g0) + fabsf(g1) + fabsf(g2) + fabsf(g3)) > 0.0f;
    s_flag[tid] = vg ? ((c < 0) ? 1 : ((c > 0) ? 2 : 0)) : 0;
  }
  __syncthreads();

  // ---- Key chain, jax_threefry_partitionable=True (JAX >= 0.4.36 default) ----
  // root = key(42) = (0, 42)
  // split(root, B)[b]   = both words of TF(root, hi=0, lo=b)
  // split(img, 2)       = kp: TF(img,0,0), kn: TF(img,0,1)
  // random_bits(k,(N,)) = TF(k, 0, i).o0 ^ .o1
  uint32_t ik0, ik1, kp0, kp1, kn0, kn1;
  threefry(0u, 42u, 0u, (uint32_t)b, ik0, ik1);
  threefry(ik0, ik1, 0u, 0u, kp0, kp1);
  threefry(ik0, ik1, 0u, 1u, kn0, kn1);

  // ---- Per-proposal: uniform bits + pos/neg masks ----
  for (int i = tid; i < N_PROP; i += NT) {
    uint32_t pa, pbx, na, nbx;
    threefry(kp0, kp1, 0u, (uint32_t)i, pa, pbx);
    threefry(kn0, kn1, 0u, (uint32_t)i, na, nbx);
    uint32_t pbits = pa ^ pbx;
    uint32_t nbits = na ^ nbx;
    const float* pr = proposals + ((size_t)b * N_PROP + i) * 4;
    float y11 = pr[0], x11 = pr[1], y12 = pr[2], x12 = pr[3];
    bool validp = (fabsf(y11) + fabsf(x11) + fabsf(y12) + fabsf(x12)) > 0.0f;
    float area1 = (y12 - y11) * (x12 - x11);
    float rmax = -1.0f, cmax = -1.0f;
    for (int g = 0; g < MAX_GT; g++) {
      int fl = s_flag[g];
      if (fl == 0) continue;
      float g0 = s_gt[g][0], g1 = s_gt[g][1], g2 = s_gt[g][2], g3 = s_gt[g][3];
      float ih = fmaxf(fminf(y12, g2) - fmaxf(y11, g0), 0.0f);
      float iw = fmaxf(fminf(x12, g3) - fmaxf(x11, g1), 0.0f);
      float inter = ih * iw;
      float uni = (area1 + (g2 - g0) * (g3 - g1)) - inter;
      float iou = (uni > 0.0f) ? (inter / uni) : 0.0f;
      if (fl == 2) rmax = fmaxf(rmax, iou);
      else         cmax = fmaxf(cmax, iou);
    }
    bool pos = validp && (rmax >= 0.5f);
    bool neg = validp && (rmax < 0.5f) && (cmax < 1e-3f);
    if (pos) atomicAdd(&s_cnt[0], 1);
    if (neg) atomicAdd(&s_cnt[1], 1);
    s_ps[i] = pos ? bits_to_uniform(pbits) : -1.0f;
    s_ns[i] = neg ? bits_to_uniform(nbits) : -1.0f;
  }
  __syncthreads();

  const int p = min(s_cnt[0], POS_CAP);
  const float INV_RATIO = (float)(1.0 / 0.33);
  const int neg_needed = (int)(INV_RATIO * (float)p) - p;
  const int n = min(min(s_cnt[1], neg_needed), NEG_CAP);

  float* out_rois = out;                                   // [B,200,4]
  float* out_cls  = out + (size_t)B * TRAIN_ROIS * 4;      // [B,200]
  float* out_del  = out_cls + (size_t)B * TRAIN_ROIS;      // [B,200,4]

  // zero this image's rois/class/deltas (d_out is poisoned each launch)
  for (int t = tid; t < TRAIN_ROIS * 4; t += NT) out_rois[(size_t)b * TRAIN_ROIS * 4 + t] = 0.0f;
  for (int t = tid; t < TRAIN_ROIS; t += NT)     out_cls[(size_t)b * TRAIN_ROIS + t] = 0.0f;
  for (int t = tid; t < TRAIN_ROIS * 4; t += NT) out_del[(size_t)b * TRAIN_ROIS * 4 + t] = 0.0f;

  // ---- exact top_k rank (stable, lower index wins ties) ----
  for (int i = tid; i < N_PROP; i += NT) {
    float s = s_ps[i];
    if (s >= 0.0f) {
      int rank = 0;
      for (int j = 0; j < N_PROP; j++) {
        float sj = s_ps[j];
        rank += (int)((sj > s) || (sj == s && j < i));
      }
      if (rank < p) s_selpos[rank] = i;
    }
    float sn = s_ns[i];
    if (sn >= 0.0f) {
      int rank = 0;
      for (int j = 0; j < N_PROP; j++) {
        float sj = s_ns[j];
        rank += (int)((sj > sn) || (sj == sn && j < i));
      }
      if (rank < n) s_selneg[rank] = i;
    }
  }
  __syncthreads();

  if (tid == 0) { ws_meta[b * 72 + 0] = p; ws_meta[b * 72 + 1] = n; }

  if (tid < p) {
    int i = s_selpos[tid];
    const float* pr = proposals + ((size_t)b * N_PROP + i) * 4;
    float y1 = pr[0], x1 = pr[1], y2 = pr[2], x2 = pr[3];
    // argmax over overlaps row (noncrowd ? iou : -1), first-max wins
    float area1 = (y2 - y1) * (x2 - x1);
    float best = -2.0f; int bg = 0;
    for (int g = 0; g < MAX_GT; g++) {
      float v = -1.0f;
      if (s_flag[g] == 2) {
        float g0 = s_gt[g][0], g1 = s_gt[g][1], g2 = s_gt[g][2], g3 = s_gt[g][3];
        float ih = fmaxf(fminf(y2, g2) - fmaxf(y1, g0), 0.0f);
        float iw = fmaxf(fminf(x2, g3) - fmaxf(x1, g1), 0.0f);
        float inter = ih * iw;
        float uni = (area1 + (g2 - g0) * (g3 - g1)) - inter;
        v = (uni > 0.0f) ? (inter / uni) : 0.0f;
      }
      if (v > best) { best = v; bg = g; }
    }
    size_t ro = ((size_t)b * TRAIN_ROIS + tid) * 4;
    out_rois[ro + 0] = y1; out_rois[ro + 1] = x1;
    out_rois[ro + 2] = y2; out_rois[ro + 3] = x2;
    out_cls[(size_t)b * TRAIN_ROIS + tid] = (float)s_cls[bg];
    float hh = y2 - y1, ww = x2 - x1;
    float cy = y1 + 0.5f * hh, cx = x1 + 0.5f * ww;
    float g0 = s_gt[bg][0], g1 = s_gt[bg][1], g2 = s_gt[bg][2], g3 = s_gt[bg][3];
    float gh = g2 - g0, gw = g3 - g1;
    float gcy = g0 + 0.5f * gh, gcx = g1 + 0.5f * gw;
    out_del[ro + 0] = ((gcy - cy) / hh) / 0.1f;
    out_del[ro + 1] = ((gcx - cx) / ww) / 0.1f;
    out_del[ro + 2] = logf(gh / hh) / 0.2f;
    out_del[ro + 3] = logf(gw / ww) / 0.2f;
    ws_meta[b * 72 + 2 + tid] = bg;
    float* wb = ws_boxes + ((size_t)b * POS_CAP + tid) * 4;
    wb[0] = y1; wb[1] = x1; wb[2] = y2; wb[3] = x2;
  }
  if (tid < n) {
    int i = s_selneg[tid];
    const float* pr = proposals + ((size_t)b * N_PROP + i) * 4;
    size_t ro = ((size_t)b * TRAIN_ROIS + p + tid) * 4;
    out_rois[ro + 0] = pr[0]; out_rois[ro + 1] = pr[1];
    out_rois[ro + 2] = pr[2]; out_rois[ro + 3] = pr[3];
  }
}

// Kernel 2: crop_and_resize + round for masks. One block per (image, output row).
__global__ __launch_bounds__(256) void dtl_masks(
    const float* __restrict__ gt_masks,   // [B, IMG_H, IMG_W, MAX_GT]
    const int* __restrict__ ws_meta,
    const float* __restrict__ ws_boxes,
    float* __restrict__ out_masks)        // [B, TRAIN_ROIS, 28, 28]
{
#pragma clang fp contract(off)
  const int blk = blockIdx.x;
  const int b = blk / TRAIN_ROIS;
  const int r = blk % TRAIN_ROIS;
  const int p = ws_meta[b * 72 + 0];
  float* dst = out_masks + ((size_t)(b * TRAIN_ROIS + r)) * (MASK_H * MASK_W);
  if (r >= p) {
    for (int t = threadIdx.x; t < MASK_H * MASK_W; t += blockDim.x) dst[t] = 0.0f;
    return;
  }
  const int g = ws_meta[b * 72 + 2 + r];
  const float* wb = ws_boxes + ((size_t)b * POS_CAP + r) * 4;
  float y1 = wb[0], x1 = wb[1], y2 = wb[2], x2 = wb[3];
  float stepy = (y2 - y1) * 1023.0f / 27.0f;
  float stepx = (x2 - x1) * 1023.0f / 27.0f;
  const float* img = gt_masks + (size_t)b * IMG_H * IMG_W * MAX_GT + g;
  for (int t = threadIdx.x; t < MASK_H * MASK_W; t += blockDim.x) {
    int my = t / MASK_W, mx = t % MASK_W;
    float ys = y1 * 1023.0f + (float)my * stepy;
    float xs = x1 * 1023.0f + (float)mx * stepx;
    float y0f = floorf(ys), x0f = floorf(xs);
    float wy = ys - y0f, wx = xs - x0f;
    int y0i = (int)fminf(fmaxf(y0f, 0.0f), 1023.0f);
    int y1i = (int)fminf(fmaxf(y0f + 1.0f, 0.0f), 1023.0f);
    int x0i = (int)fminf(fmaxf(x0f, 0.0f), 1023.0f);
    int x1i = (int)fminf(fmaxf(x0f + 1.0f, 0.0f), 1023.0f);
    float v00 = img[(size_t)(y0i * IMG_W + x0i) * MAX_GT];
    float v01 = img[(size_t)(y0i * IMG_W + x1i) * MAX_GT];
    float v10 = img[(size_t)(y1i * IMG_W + x0i) * MAX_GT];
    float v11 = img[(size_t)(y1i * IMG_W + x1i) * MAX_GT];
    float top = v00 * (1.0f - wx) + v01 * wx;
    float bot = v10 * (1.0f - wx) + v11 * wx;
    float o = top * (1.0f - wy) + bot * wy;
    bool valid = (ys >= 0.0f) && (ys <= 1023.0f) && (xs >= 0.0f) && (xs <= 1023.0f);
    o = valid ? o : 0.0f;
    dst[t] = rintf(o);   // round half to even, matches jnp.round
  }
}

extern "C" void kernel_launch(void* const* d_in, const int* in_sizes, int n_in,
                              void* d_out, int out_size, void* d_ws, size_t ws_size,
                              hipStream_t stream) {
  const float* proposals    = (const float*)d_in[0];
  const int*   gt_class_ids = (const int*)d_in[1];
  const float* gt_boxes     = (const float*)d_in[2];
  const float* gt_masks     = (const float*)d_in[3];
  float* out = (float*)d_out;
  int*   ws_meta  = (int*)d_ws;
  float* ws_boxes = (float*)((char*)d_ws + 1024);

  dtl_select<<<B, 1024, 0, stream>>>(proposals, gt_class_ids, gt_boxes,
                                     out, ws_meta, ws_boxes);

  float* out_msk = out + (size_t)B * TRAIN_ROIS * 4   // rois
                       + (size_t)B * TRAIN_ROIS        // class_ids
                       + (size_t)B * TRAIN_ROIS * 4;   // deltas
  dtl_masks<<<B * TRAIN_ROIS, 256, 0, stream>>>(gt_masks, ws_meta, ws_boxes, out_msk);
}

// Round 3
// 545.835 us; speedup vs baseline: 1.5028x; 1.5028x over previous
//
#include <hip/hip_runtime.h>
#include <stdint.h>

#define B 2
#define N_PROP 2000
#define NPAD 2048
#define MAX_GT 50
#define IMG_H 1024
#define IMG_W 1024
#define TRAIN_ROIS 200
#define POS_CAP 66
#define NEG_CAP 134
#define MASK_H 28
#define MASK_W 28

// ws layout:
//   0      : float ws_ps[B][NPAD]   (16 KB)
//   16384  : float ws_ns[B][NPAD]   (16 KB)
//   32768  : int   ws_sel[B][512]   ([0]=p, [1]=n, [2..67]=selpos, [68..201]=selneg,
//                                    [202..267]=gt assignment per positive)

// JAX threefry2x32: 20 rounds, key injection every 4 rounds.
__device__ __forceinline__ void threefry(uint32_t k0, uint32_t k1,
                                         uint32_t x0, uint32_t x1,
                                         uint32_t& o0, uint32_t& o1) {
  uint32_t k2 = k0 ^ k1 ^ 0x1BD11BDAu;
  x0 += k0; x1 += k1;
#define TF_R(r) { x0 += x1; x1 = (x1 << (r)) | (x1 >> (32 - (r))); x1 ^= x0; }
  TF_R(13) TF_R(15) TF_R(26) TF_R(6)
  x0 += k1; x1 += k2 + 1u;
  TF_R(17) TF_R(29) TF_R(16) TF_R(24)
  x0 += k2; x1 += k0 + 2u;
  TF_R(13) TF_R(15) TF_R(26) TF_R(6)
  x0 += k0; x1 += k1 + 3u;
  TF_R(17) TF_R(29) TF_R(16) TF_R(24)
  x0 += k1; x1 += k2 + 4u;
  TF_R(13) TF_R(15) TF_R(26) TF_R(6)
  x0 += k2; x1 += k0 + 5u;
#undef TF_R
  o0 = x0; o1 = x1;
}

__device__ __forceinline__ float bits_to_uniform(uint32_t bits) {
  return __uint_as_float((bits >> 9) | 0x3F800000u) - 1.0f;
}

// Kernel A: per-proposal masks + threefry scores. grid = B*8 blocks x 256.
__global__ __launch_bounds__(256) void dtl_scores(
    const float* __restrict__ proposals,   // [B, N_PROP, 4]
    const int* __restrict__ gt_class_ids,  // [B, MAX_GT]
    const float* __restrict__ gt_boxes,    // [B, MAX_GT, 4]
    float* __restrict__ ws_ps,             // [B, NPAD]
    float* __restrict__ ws_ns)             // [B, NPAD]
{
#pragma clang fp contract(off)
  const int b = blockIdx.x >> 3;
  const int blk8 = blockIdx.x & 7;
  const int tid = threadIdx.x;

  __shared__ float s_gt[MAX_GT][4];
  __shared__ int   s_flag[MAX_GT];   // 0 invalid, 1 crowd, 2 noncrowd
  if (tid < MAX_GT) {
    float g0 = gt_boxes[((size_t)b * MAX_GT + tid) * 4 + 0];
    float g1 = gt_boxes[((size_t)b * MAX_GT + tid) * 4 + 1];
    float g2 = gt_boxes[((size_t)b * MAX_GT + tid) * 4 + 2];
    float g3 = gt_boxes[((size_t)b * MAX_GT + tid) * 4 + 3];
    s_gt[tid][0] = g0; s_gt[tid][1] = g1; s_gt[tid][2] = g2; s_gt[tid][3] = g3;
    int c = gt_class_ids[b * MAX_GT + tid];
    bool vg = (fabsf(g0) + fabsf(g1) + fabsf(g2) + fabsf(g3)) > 0.0f;
    s_flag[tid] = vg ? ((c < 0) ? 1 : ((c > 0) ? 2 : 0)) : 0;
  }
  __syncthreads();

  const int i = blk8 * 256 + tid;   // i < 2048 always
  float ps = -1.0f, ns = -1.0f;
  if (i < N_PROP) {
    // key chain (jax_threefry_partitionable=True):
    // root=key(42)=(0,42); img=TF(root,0,b); kp=TF(img,0,0); kn=TF(img,0,1)
    // bits[i] = TF(k,0,i).o0 ^ .o1
    uint32_t ik0, ik1, kp0, kp1, kn0, kn1;
    threefry(0u, 42u, 0u, (uint32_t)b, ik0, ik1);
    threefry(ik0, ik1, 0u, 0u, kp0, kp1);
    threefry(ik0, ik1, 0u, 1u, kn0, kn1);
    uint32_t pa, pb2, na, nb2;
    threefry(kp0, kp1, 0u, (uint32_t)i, pa, pb2);
    threefry(kn0, kn1, 0u, (uint32_t)i, na, nb2);

    const float* pr = proposals + ((size_t)b * N_PROP + i) * 4;
    float y11 = pr[0], x11 = pr[1], y12 = pr[2], x12 = pr[3];
    bool validp = (fabsf(y11) + fabsf(x11) + fabsf(y12) + fabsf(x12)) > 0.0f;
    float area1 = (y12 - y11) * (x12 - x11);
    float rmax = -1.0f, cmax = -1.0f;
    for (int g = 0; g < MAX_GT; g++) {
      int fl = s_flag[g];
      if (fl == 0) continue;
      float g0 = s_gt[g][0], g1 = s_gt[g][1], g2 = s_gt[g][2], g3 = s_gt[g][3];
      float ih = fmaxf(fminf(y12, g2) - fmaxf(y11, g0), 0.0f);
      float iw = fmaxf(fminf(x12, g3) - fmaxf(x11, g1), 0.0f);
      float inter = ih * iw;
      float uni = (area1 + (g2 - g0) * (g3 - g1)) - inter;
      float iou = (uni > 0.0f) ? (inter / uni) : 0.0f;
      if (fl == 2) rmax = fmaxf(rmax, iou);
      else         cmax = fmaxf(cmax, iou);
    }
    bool pos = validp && (rmax >= 0.5f);
    bool neg = validp && (rmax < 0.5f) && (cmax < 1e-3f);
    ps = pos ? bits_to_uniform(pa ^ pb2) : -1.0f;
    ns = neg ? bits_to_uniform(na ^ nb2) : -1.0f;
  }
  ws_ps[b * NPAD + i] = ps;
  ws_ns[b * NPAD + i] = ns;
}

// Kernel B: exact top_k rank via LDS float4 scan. grid = B*8 blocks x 256.
__global__ __launch_bounds__(256) void dtl_rank(
    const float* __restrict__ ws_ps,
    const float* __restrict__ ws_ns,
    int* __restrict__ ws_sel)
{
  const int b = blockIdx.x >> 3;
  const int blk8 = blockIdx.x & 7;
  const int tid = threadIdx.x;

  __shared__ __align__(16) float s_ps[NPAD];
  __shared__ __align__(16) float s_ns[NPAD];
  __shared__ int s_cnt[2];

  if (tid < 2) s_cnt[tid] = 0;

  const float4* gp = (const float4*)(ws_ps + (size_t)b * NPAD);
  const float4* gn = (const float4*)(ws_ns + (size_t)b * NPAD);
  float4 p0 = gp[tid], p1 = gp[tid + 256];
  float4 q0 = gn[tid], q1 = gn[tid + 256];
  int lcp = (p0.x >= 0.0f) + (p0.y >= 0.0f) + (p0.z >= 0.0f) + (p0.w >= 0.0f)
          + (p1.x >= 0.0f) + (p1.y >= 0.0f) + (p1.z >= 0.0f) + (p1.w >= 0.0f);
  int lcn = (q0.x >= 0.0f) + (q0.y >= 0.0f) + (q0.z >= 0.0f) + (q0.w >= 0.0f)
          + (q1.x >= 0.0f) + (q1.y >= 0.0f) + (q1.z >= 0.0f) + (q1.w >= 0.0f);
  for (int off = 32; off; off >>= 1) {
    lcp += __shfl_down(lcp, off);
    lcn += __shfl_down(lcn, off);
  }
  __syncthreads();                       // s_cnt zero visible
  if ((tid & 63) == 0) { atomicAdd(&s_cnt[0], lcp); atomicAdd(&s_cnt[1], lcn); }
  float4* sp4 = (float4*)s_ps;
  float4* sn4 = (float4*)s_ns;
  sp4[tid] = p0; sp4[tid + 256] = p1;
  sn4[tid] = q0; sn4[tid + 256] = q1;
  __syncthreads();

  const int p = min(s_cnt[0], POS_CAP);
  const float INV_RATIO = (float)(1.0 / 0.33);
  const int neg_needed = (int)(INV_RATIO * (float)p) - p;
  const int n = min(min(s_cnt[1], neg_needed), NEG_CAP);

  const int i = blk8 * 256 + tid;
  if (i < N_PROP) {
    float sp = s_ps[i], sn = s_ns[i];
    bool isp = sp >= 0.0f;
    bool isn = sn >= 0.0f;
    if (isp || isn) {
      float s = isp ? sp : sn;
      const float4* arr = isp ? (const float4*)s_ps : (const float4*)s_ns;
      int rank = 0;
      for (int j = 0; j < NPAD / 4; j++) {
        float4 v = arr[j];
        int jj = j * 4;
        rank += (int)((v.x > s) || (v.x == s && (jj    ) < i));
        rank += (int)((v.y > s) || (v.y == s && (jj + 1) < i));
        rank += (int)((v.z > s) || (v.z == s && (jj + 2) < i));
        rank += (int)((v.w > s) || (v.w == s && (jj + 3) < i));
      }
      if (isp) { if (rank < p) ws_sel[b * 512 + 2 + rank] = i; }
      else     { if (rank < n) ws_sel[b * 512 + 68 + rank] = i; }
    }
  }
  if (blk8 == 0 && tid == 0) { ws_sel[b * 512 + 0] = p; ws_sel[b * 512 + 1] = n; }
}

// Kernel C: write rois / class_ids / deltas + gt assignment. grid = B x 256.
__global__ __launch_bounds__(256) void dtl_epilogue(
    const float* __restrict__ proposals,
    const int* __restrict__ gt_class_ids,
    const float* __restrict__ gt_boxes,
    float* __restrict__ out,
    int* __restrict__ ws_sel)
{
#pragma clang fp contract(off)
  const int b = blockIdx.x;
  const int tid = threadIdx.x;

  __shared__ float s_gt[MAX_GT][4];
  __shared__ int   s_cls[MAX_GT];
  __shared__ int   s_flag[MAX_GT];
  if (tid < MAX_GT) {
    float g0 = gt_boxes[((size_t)b * MAX_GT + tid) * 4 + 0];
    float g1 = gt_boxes[((size_t)b * MAX_GT + tid) * 4 + 1];
    float g2 = gt_boxes[((size_t)b * MAX_GT + tid) * 4 + 2];
    float g3 = gt_boxes[((size_t)b * MAX_GT + tid) * 4 + 3];
    s_gt[tid][0] = g0; s_gt[tid][1] = g1; s_gt[tid][2] = g2; s_gt[tid][3] = g3;
    int c = gt_class_ids[b * MAX_GT + tid];
    s_cls[tid] = c;
    bool vg = (fabsf(g0) + fabsf(g1) + fabsf(g2) + fabsf(g3)) > 0.0f;
    s_flag[tid] = vg ? ((c < 0) ? 1 : ((c > 0) ? 2 : 0)) : 0;
  }

  const int p = ws_sel[b * 512 + 0];
  const int n = ws_sel[b * 512 + 1];

  float* out_rois = out;
  float* out_cls  = out + (size_t)B * TRAIN_ROIS * 4;
  float* out_del  = out_cls + (size_t)B * TRAIN_ROIS;

  for (int t = tid; t < TRAIN_ROIS * 4; t += 256) out_rois[(size_t)b * TRAIN_ROIS * 4 + t] = 0.0f;
  for (int t = tid; t < TRAIN_ROIS; t += 256)     out_cls[(size_t)b * TRAIN_ROIS + t] = 0.0f;
  for (int t = tid; t < TRAIN_ROIS * 4; t += 256) out_del[(size_t)b * TRAIN_ROIS * 4 + t] = 0.0f;
  __syncthreads();   // zeroing + gt staging complete before row writes

  if (tid < p) {
    int i = ws_sel[b * 512 + 2 + tid];
    const float* pr = proposals + ((size_t)b * N_PROP + i) * 4;
    float y1 = pr[0], x1 = pr[1], y2 = pr[2], x2 = pr[3];
    float area1 = (y2 - y1) * (x2 - x1);
    float best = -2.0f; int bg = 0;
    for (int g = 0; g < MAX_GT; g++) {
      float v = -1.0f;
      if (s_flag[g] == 2) {
        float g0 = s_gt[g][0], g1 = s_gt[g][1], g2 = s_gt[g][2], g3 = s_gt[g][3];
        float ih = fmaxf(fminf(y2, g2) - fmaxf(y1, g0), 0.0f);
        float iw = fmaxf(fminf(x2, g3) - fmaxf(x1, g1), 0.0f);
        float inter = ih * iw;
        float uni = (area1 + (g2 - g0) * (g3 - g1)) - inter;
        v = (uni > 0.0f) ? (inter / uni) : 0.0f;
      }
      if (v > best) { best = v; bg = g; }
    }
    size_t ro = ((size_t)b * TRAIN_ROIS + tid) * 4;
    out_rois[ro + 0] = y1; out_rois[ro + 1] = x1;
    out_rois[ro + 2] = y2; out_rois[ro + 3] = x2;
    out_cls[(size_t)b * TRAIN_ROIS + tid] = (float)s_cls[bg];
    float hh = y2 - y1, ww = x2 - x1;
    float cy = y1 + 0.5f * hh, cx = x1 + 0.5f * ww;
    float g0 = s_gt[bg][0], g1 = s_gt[bg][1], g2 = s_gt[bg][2], g3 = s_gt[bg][3];
    float gh = g2 - g0, gw = g3 - g1;
    float gcy = g0 + 0.5f * gh, gcx = g1 + 0.5f * gw;
    out_del[ro + 0] = ((gcy - cy) / hh) / 0.1f;
    out_del[ro + 1] = ((gcx - cx) / ww) / 0.1f;
    out_del[ro + 2] = logf(gh / hh) / 0.2f;
    out_del[ro + 3] = logf(gw / ww) / 0.2f;
    ws_sel[b * 512 + 202 + tid] = bg;
  }
  if (tid < n) {
    int i = ws_sel[b * 512 + 68 + tid];
    const float* pr = proposals + ((size_t)b * N_PROP + i) * 4;
    size_t ro = ((size_t)b * TRAIN_ROIS + p + tid) * 4;
    out_rois[ro + 0] = pr[0]; out_rois[ro + 1] = pr[1];
    out_rois[ro + 2] = pr[2]; out_rois[ro + 3] = pr[3];
  }
}

// Kernel D: crop_and_resize + round. grid = B*TRAIN_ROIS x 1024, 1 px/thread.
__global__ __launch_bounds__(1024) void dtl_masks(
    const float* __restrict__ gt_masks,   // [B, IMG_H, IMG_W, MAX_GT]
    const int* __restrict__ ws_sel,
    const float* __restrict__ out_rois,   // d_out rois region, written by epilogue
    float* __restrict__ out_masks)        // [B, TRAIN_ROIS, 28, 28]
{
#pragma clang fp contract(off)
  const int blk = blockIdx.x;
  const int b = blk / TRAIN_ROIS;
  const int r = blk % TRAIN_ROIS;
  const int p = ws_sel[b * 512 + 0];
  float* dst = out_masks + ((size_t)(b * TRAIN_ROIS + r)) * (MASK_H * MASK_W);
  const int t = threadIdx.x;
  if (r >= p) {
    if (t < MASK_H * MASK_W) dst[t] = 0.0f;
    return;
  }
  const int g = ws_sel[b * 512 + 202 + r];
  const float* roi = out_rois + ((size_t)(b * TRAIN_ROIS + r)) * 4;
  float y1 = roi[0], x1 = roi[1], y2 = roi[2], x2 = roi[3];
  float stepy = (y2 - y1) * 1023.0f / 27.0f;
  float stepx = (x2 - x1) * 1023.0f / 27.0f;
  const float* img = gt_masks + (size_t)b * IMG_H * IMG_W * MAX_GT + g;
  if (t < MASK_H * MASK_W) {
    int my = t / MASK_W, mx = t % MASK_W;
    float ys = y1 * 1023.0f + (float)my * stepy;
    float xs = x1 * 1023.0f + (float)mx * stepx;
    float y0f = floorf(ys), x0f = floorf(xs);
    float wy = ys - y0f, wx = xs - x0f;
    int y0i = (int)fminf(fmaxf(y0f, 0.0f), 1023.0f);
    int y1i = (int)fminf(fmaxf(y0f + 1.0f, 0.0f), 1023.0f);
    int x0i = (int)fminf(fmaxf(x0f, 0.0f), 1023.0f);
    int x1i = (int)fminf(fmaxf(x0f + 1.0f, 0.0f), 1023.0f);
    float v00 = img[(size_t)(y0i * IMG_W + x0i) * MAX_GT];
    float v01 = img[(size_t)(y0i * IMG_W + x1i) * MAX_GT];
    float v10 = img[(size_t)(y1i * IMG_W + x0i) * MAX_GT];
    float v11 = img[(size_t)(y1i * IMG_W + x1i) * MAX_GT];
    float top = v00 * (1.0f - wx) + v01 * wx;
    float bot = v10 * (1.0f - wx) + v11 * wx;
    float o = top * (1.0f - wy) + bot * wy;
    bool valid = (ys >= 0.0f) && (ys <= 1023.0f) && (xs >= 0.0f) && (xs <= 1023.0f);
    o = valid ? o : 0.0f;
    dst[t] = rintf(o);   // round half to even, matches jnp.round
  }
}

extern "C" void kernel_launch(void* const* d_in, const int* in_sizes, int n_in,
                              void* d_out, int out_size, void* d_ws, size_t ws_size,
                              hipStream_t stream) {
  const float* proposals    = (const float*)d_in[0];
  const int*   gt_class_ids = (const int*)d_in[1];
  const float* gt_boxes     = (const float*)d_in[2];
  const float* gt_masks     = (const float*)d_in[3];
  float* out = (float*)d_out;

  float* ws_ps  = (float*)d_ws;
  float* ws_ns  = (float*)((char*)d_ws + 16384);
  int*   ws_sel = (int*)((char*)d_ws + 32768);

  dtl_scores<<<B * 8, 256, 0, stream>>>(proposals, gt_class_ids, gt_boxes, ws_ps, ws_ns);
  dtl_rank<<<B * 8, 256, 0, stream>>>(ws_ps, ws_ns, ws_sel);
  dtl_epilogue<<<B, 256, 0, stream>>>(proposals, gt_class_ids, gt_boxes, out, ws_sel);

  float* out_msk = out + (size_t)B * TRAIN_ROIS * 4
                       + (size_t)B * TRAIN_ROIS
                       + (size_t)B * TRAIN_ROIS * 4;
  dtl_masks<<<B * TRAIN_ROIS, 1024, 0, stream>>>(gt_masks, ws_sel, out, out_msk);
}